// Round 5
// baseline (86.609 us; speedup 1.0000x reference)
//
#include <hip/hip_runtime.h>
#include <hip/hip_bf16.h>

#define IN_CAPS 32
#define OUT_CAPS 10
#define NOUT 160      // OUT_CAPS*OUT_DIM
#define KDIM 288
#define BATCH 4096
#define KSTEPS 9      // 288/32
#define CTILES 10     // 160/16
#define STR2 162      // LDS ushort stride for u rows in routing

typedef __bf16 bf16x8 __attribute__((ext_vector_type(8)));
typedef float  f32x4  __attribute__((ext_vector_type(4)));
typedef __attribute__((address_space(1))) void as1_t;
typedef __attribute__((address_space(3))) void as3_t;

// ---------------------------------------------------------------------------
// prep_w: W f32 [32][288][160] -> bf16 in per-lane MFMA B-fragment order:
//   Wf[((n*9+ks)*10+ct)*512 + lane*8 + j] = W[n][ks*32+(lane>>4)*8+j][ct*16+(lane&15)]
// ---------------------------------------------------------------------------
__global__ __launch_bounds__(256) void prep_w(const float* __restrict__ W,
                                              __bf16* __restrict__ Wf) {
    int f = blockIdx.x * 256 + threadIdx.x;   // grid covers exactly 32*9*10*512
    int j    = f & 7;
    int l    = (f >> 3) & 63;
    int rest = f >> 9;
    int c    = rest % CTILES;
    int tnk  = rest / CTILES;
    int ks   = tnk % KSTEPS;
    int n    = tnk / KSTEPS;
    int k    = ks * 32 + (l >> 4) * 8 + j;
    int col  = c * 16 + (l & 15);
    Wf[f] = (__bf16)W[(n * KDIM + k) * NOUT + col];
}

// ---------------------------------------------------------------------------
// gemm_u v4: 16 rows/wave (acc = 40 VGPR -> 4 waves/SIMD). A staged f32 via
// global_load_lds width-16 into per-wave LDS slices -> NO barriers at all;
// per-wave counted s_waitcnt vmcnt(2), depth-2 pipeline over 3 buffers.
// LDS bank fix (rule #21): XOR-swizzle the global SOURCE chunk (c ^= r&7),
// glds dest stays lane-linear, same XOR on the ds_read address -> 2-way max.
// ---------------------------------------------------------------------------
__global__ __launch_bounds__(256) void gemm_u(const float* __restrict__ caps,
                                              const __bf16* __restrict__ Wf,
                                              uint4* __restrict__ up) {
    __shared__ float abuf[3][64 * 32];        // 3 x 8KB, per-wave 2KB slices

    const int n    = blockIdx.y;              // capsule 0..31
    const int rb   = blockIdx.x;              // 64-row block, 0..63
    const int w    = threadIdx.x >> 6;
    const int lane = threadIdx.x & 63;
    const int lm   = lane & 15;
    const int lk   = lane >> 4;

    // glds slot geometry: instruction q in {0,1}: slot s = w*128 + q*64 + lane
    // r = s>>3 (local row), source chunk c = (s&7) ^ (r&7)  [inverse swizzle]
    const int s0 = w * 128 + lane;
    const int s1 = s0 + 64;
    const int r0 = s0 >> 3;
    const int r1 = s1 >> 3;
    const int c0 = (s0 & 7) ^ (r0 & 7);
    const int c1 = (s1 & 7) ^ (r1 & 7);
    const float* g0 = caps + (size_t)(rb * 64 + r0) * (IN_CAPS * KDIM) + n * KDIM + c0 * 4;
    const float* g1 = caps + (size_t)(rb * 64 + r1) * (IN_CAPS * KDIM) + n * KDIM + c1 * 4;

    f32x4 acc[CTILES];
#pragma unroll
    for (int ct = 0; ct < CTILES; ++ct) acc[ct] = (f32x4){0.f, 0.f, 0.f, 0.f};

    // read-side: row rloc, k-chunks (2lk, 2lk+1), swizzled by lm&7
    const int rloc = w * 16 + lm;
    const int h0   = ((lk * 2)     ^ (lm & 7)) * 4;
    const int h1   = ((lk * 2 + 1) ^ (lm & 7)) * 4;
    const __bf16* wfn = Wf + (size_t)n * (KSTEPS * CTILES * 512) + lane * 8;

    // prologue: stage ks=0 -> buf0, ks=1 -> buf1 (per-wave slices, no barrier)
    __builtin_amdgcn_global_load_lds((const as1_t*)g0, (as3_t*)&abuf[0][w * 512],       16, 0, 0);
    __builtin_amdgcn_global_load_lds((const as1_t*)g1, (as3_t*)&abuf[0][w * 512 + 256], 16, 0, 0);
    __builtin_amdgcn_global_load_lds((const as1_t*)(g0 + 32), (as3_t*)&abuf[1][w * 512],       16, 0, 0);
    __builtin_amdgcn_global_load_lds((const as1_t*)(g1 + 32), (as3_t*)&abuf[1][w * 512 + 256], 16, 0, 0);

#pragma unroll
    for (int ks = 0; ks < KSTEPS; ++ks) {
        // wait for this ks's stage: allow the (ks+1) stage (2 glds) to remain
        if (ks + 1 < KSTEPS) asm volatile("s_waitcnt vmcnt(2)" ::: "memory");
        else                 asm volatile("s_waitcnt vmcnt(0)" ::: "memory");

        const float* bc = abuf[ks % 3];
        f32x4 x0 = *(const f32x4*)&bc[rloc * 32 + h0];
        f32x4 x1 = *(const f32x4*)&bc[rloc * 32 + h1];
        bf16x8 a;
        a[0] = (__bf16)x0[0]; a[1] = (__bf16)x0[1];
        a[2] = (__bf16)x0[2]; a[3] = (__bf16)x0[3];
        a[4] = (__bf16)x1[0]; a[5] = (__bf16)x1[1];
        a[6] = (__bf16)x1[2]; a[7] = (__bf16)x1[3];

        const __bf16* wks = wfn + (size_t)ks * (CTILES * 512);
#pragma unroll
        for (int ct = 0; ct < CTILES; ++ct) {
            bf16x8 bfr = *(const bf16x8*)(wks + ct * 512);
            acc[ct] = __builtin_amdgcn_mfma_f32_16x16x32_bf16(a, bfr, acc[ct], 0, 0, 0);
        }

        // stage ks+2 AFTER the MFMAs (keeps compiler's B-load waits clean)
        if (ks + 2 < KSTEPS) {
            float* dst = &abuf[(ks + 2) % 3][0];
            __builtin_amdgcn_global_load_lds((const as1_t*)(g0 + (ks + 2) * 32),
                                             (as3_t*)(dst + w * 512),       16, 0, 0);
            __builtin_amdgcn_global_load_lds((const as1_t*)(g1 + (ks + 2) * 32),
                                             (as3_t*)(dst + w * 512 + 256), 16, 0, 0);
        }
    }

    // epilogue: permuted coalesced store, same chunk layout as R3/R4:
    //   idx = (((n*128 + rw)*2 + mt)*5 + p)*64 + lane
    const int rw = rb * 2 + (w >> 1);
    const int mt = w & 1;
    const size_t cbase = ((((size_t)n * 128 + rw) * 2 + mt) * 5) * 64 + lane;
#pragma unroll
    for (int p = 0; p < 5; ++p) {
        bf16x8 pk;
#pragma unroll
        for (int j = 0; j < 8; ++j)
            pk[j] = (__bf16)acc[2 * p + (j >> 2)][j & 3];
        up[cbase + (size_t)p * 64] = __builtin_bit_cast(uint4, pk);
    }
}

// ---------------------------------------------------------------------------
// routing v3 (unchanged from R4): 4 consecutive batch rows per block.
// ---------------------------------------------------------------------------
__global__ __launch_bounds__(256) void routing(const uint4* __restrict__ up,
                                               const float* __restrict__ bbias,
                                               float* __restrict__ out) {
    __shared__ __bf16 ul[4][IN_CAPS * STR2];      // 41472 B
    __shared__ float  bl[4][IN_CAPS * OUT_CAPS];
    __shared__ float  cs[4][IN_CAPS * OUT_CAPS];
    __shared__ float  ss[4][NOUT];
    __shared__ float  vs[4][NOUT];
    __shared__ float  scale_s[4][16];

    const int t  = threadIdx.x;
    const int b0 = blockIdx.x * 4;
    const int rw = b0 >> 5;
    const int mt = (b0 >> 4) & 1;
    const int lk = (b0 >> 2) & 3;

    for (int c = t; c < 2560; c += 256) {
        int n   = c / 80;
        int rem = c - n * 80;
        int p   = rem >> 4;
        int lm  = rem & 15;
        size_t idx = ((((size_t)n * 128 + rw) * 2 + mt) * 5 + p) * 64 + lk * 16 + lm;
        bf16x8 v = __builtin_bit_cast(bf16x8, up[idx]);
#pragma unroll
        for (int j = 0; j < 8; ++j) {
            int ct = 2 * p + (j >> 2);
            int rr = j & 3;
            ul[rr][n * STR2 + ct * 16 + lm] = v[j];
        }
    }
    const int grp = t >> 6;
    const int g   = t & 63;
    for (int pp = g; pp < IN_CAPS * OUT_CAPS; pp += 64) bl[grp][pp] = bbias[pp];
    __syncthreads();

    for (int it = 0; it < 4; ++it) {
        if (it > 0) {
            for (int pp = g; pp < IN_CAPS * OUT_CAPS; pp += 64) {
                int n = pp & 31;
                int o = pp >> 5;
                float a = 0.f;
#pragma unroll
                for (int d = 0; d < 16; ++d)
                    a += (float)ul[grp][n * STR2 + o * 16 + d] * vs[grp][o * 16 + d];
                bl[grp][n * 10 + o] += a;
            }
            __syncthreads();
        }
        if (g < IN_CAPS) {
            float m = bl[grp][g * 10];
#pragma unroll
            for (int o = 1; o < 10; ++o) m = fmaxf(m, bl[grp][g * 10 + o]);
            float e[10];
            float sum = 0.f;
#pragma unroll
            for (int o = 0; o < 10; ++o) { e[o] = __expf(bl[grp][g * 10 + o] - m); sum += e[o]; }
            float inv = 1.0f / sum;
#pragma unroll
            for (int o = 0; o < 10; ++o) cs[grp][g * 10 + o] = e[o] * inv;
        }
        __syncthreads();
        for (int p = g; p < NOUT; p += 64) {
            int o = p >> 4;
            float a = 0.f;
#pragma unroll
            for (int nn = 0; nn < IN_CAPS; ++nn)
                a += cs[grp][nn * 10 + o] * (float)ul[grp][nn * STR2 + p];
            ss[grp][p] = a;
        }
        __syncthreads();
        if (g < OUT_CAPS) {
            float sq = 0.f;
#pragma unroll
            for (int d = 0; d < 16; ++d) { float x = ss[grp][g * 16 + d]; sq += x * x; }
            scale_s[grp][g] = sq / ((1.0f + sq) * sqrtf(sq));
        }
        __syncthreads();
        for (int p = g; p < NOUT; p += 64) vs[grp][p] = scale_s[grp][p >> 4] * ss[grp][p];
        __syncthreads();
    }

    for (int p = g; p < NOUT; p += 64)
        out[(size_t)(b0 + grp) * NOUT + p] = vs[grp][p];
}

// ---------------------------------------------------------------------------
extern "C" void kernel_launch(void* const* d_in, const int* in_sizes, int n_in,
                              void* d_out, int out_size, void* d_ws, size_t ws_size,
                              hipStream_t stream) {
    const float* caps  = (const float*)d_in[0];   // [4096][32][288]
    const float* W     = (const float*)d_in[1];   // [32][288][160]
    const float* bbias = (const float*)d_in[2];   // [32][10]
    float* out = (float*)d_out;                   // [4096][10][16]

    __bf16* Wf = (__bf16*)d_ws;                               // 2,949,120 B
    uint4*  up = (uint4*)((char*)d_ws + 2949120);             // 41,943,040 B

    prep_w<<<dim3(5760), dim3(256), 0, stream>>>(W, Wf);
    gemm_u<<<dim3(64, 32), dim3(256), 0, stream>>>(caps, Wf, up);
    routing<<<dim3(BATCH / 4), dim3(256), 0, stream>>>(up, bbias, out);
}

// Round 6
// 78.868 us; speedup vs baseline: 1.0982x; 1.0982x over previous
//
#include <hip/hip_runtime.h>
#include <hip/hip_bf16.h>

#define IN_CAPS 32
#define OUT_CAPS 10
#define NOUT 160      // OUT_CAPS*OUT_DIM
#define KDIM 288
#define BATCH 4096
#define KSTEPS 9      // 288/32
#define CTILES 10     // 160/16
#define STR2 162      // LDS ushort stride for u rows in routing

typedef __bf16 bf16x8 __attribute__((ext_vector_type(8)));
typedef float  f32x4  __attribute__((ext_vector_type(4)));
typedef __attribute__((address_space(1))) void as1_t;
typedef __attribute__((address_space(3))) void as3_t;

// ---------------------------------------------------------------------------
// prep_w: W f32 [32][288][160] -> bf16 in per-lane MFMA B-fragment order:
//   Wf[((n*9+ks)*10+ct)*512 + lane*8 + j] = W[n][ks*32+(lane>>4)*8+j][ct*16+(lane&15)]
// ---------------------------------------------------------------------------
__global__ __launch_bounds__(256) void prep_w(const float* __restrict__ W,
                                              __bf16* __restrict__ Wf) {
    int f = blockIdx.x * 256 + threadIdx.x;   // grid covers exactly 32*9*10*512
    int j    = f & 7;
    int l    = (f >> 3) & 63;
    int rest = f >> 9;
    int c    = rest % CTILES;
    int tnk  = rest / CTILES;
    int ks   = tnk % KSTEPS;
    int n    = tnk / KSTEPS;
    int k    = ks * 32 + (l >> 4) * 8 + j;
    int col  = c * 16 + (l & 15);
    Wf[f] = (__bf16)W[(n * KDIM + k) * NOUT + col];
}

// ---------------------------------------------------------------------------
// gemm_u v5: canonical LDS-staged GEMM. R5 diagnosis: B-fragments were
// re-fetched from global per-wave per-iter (90 KB/wave through L1) ->
// latency-bound at 5% MfmaUtil. Now A AND B staged cooperatively per block:
// B read once per block from L2, all compute reads hit LDS.
//  - 64 rows x one n per block; 16 rows/wave; acc=40 VGPR.
//  - A f32 dbuf via global_load_lds w/ XOR source-swizzle (<=2-way ds_read).
//  - B bf16 dbuf via global_load_lds straight into fragment order.
//  - stage(ks+1) -> compute(ks) -> __syncthreads(): 1 sync/iter, 2 buffers.
// ---------------------------------------------------------------------------
__global__ __launch_bounds__(256) void gemm_u(const float* __restrict__ caps,
                                              const __bf16* __restrict__ Wf,
                                              uint4* __restrict__ up) {
    __shared__ float  As[2][64 * 32];     // 2 x 8 KB
    __shared__ __bf16 Bs[2][5120];        // 2 x 10 KB   => 36 KB total

    const int n    = blockIdx.y;          // capsule 0..31
    const int rb   = blockIdx.x;          // 64-row block, 0..63
    const int w    = threadIdx.x >> 6;
    const int lane = threadIdx.x & 63;
    const int lm   = lane & 15;
    const int lk   = lane >> 4;

    // ---- A staging geometry: 2 glds/wave, wave stages its own 16 rows ----
    // slot sl -> local row r = sl>>3, LDS chunk-pos = sl&7 holds source chunk
    // c = (sl&7) ^ (r&7)  (XOR involution; reader applies same XOR)
    const int sl0 = w * 128 + lane;
    const int sl1 = sl0 + 64;
    const int r0 = sl0 >> 3, r1 = sl1 >> 3;
    const int c0 = (sl0 & 7) ^ (r0 & 7);
    const int c1 = (sl1 & 7) ^ (r1 & 7);
    const float* ga0 = caps + ((size_t)(rb * 64 + r0) * IN_CAPS + n) * KDIM + c0 * 4;
    const float* ga1 = caps + ((size_t)(rb * 64 + r1) * IN_CAPS + n) * KDIM + c1 * 4;

    // ---- B staging: 10 glds of 1 KB; i = w*2, w*2+1, and 8+w for w<2 ----
    const __bf16* wb = Wf + (size_t)n * (KSTEPS * 5120);

#define STAGE(ks, buf) do {                                                          \
    __builtin_amdgcn_global_load_lds((const as1_t*)(ga0 + (ks) * 32),                \
                                     (as3_t*)&As[buf][w * 512],        16, 0, 0);    \
    __builtin_amdgcn_global_load_lds((const as1_t*)(ga1 + (ks) * 32),                \
                                     (as3_t*)&As[buf][w * 512 + 256],  16, 0, 0);    \
    __builtin_amdgcn_global_load_lds((const as1_t*)(wb + (size_t)(ks) * 5120 +       \
                                     (w * 2) * 512 + lane * 8),                      \
                                     (as3_t*)&Bs[buf][(w * 2) * 512],  16, 0, 0);    \
    __builtin_amdgcn_global_load_lds((const as1_t*)(wb + (size_t)(ks) * 5120 +       \
                                     (w * 2 + 1) * 512 + lane * 8),                  \
                                     (as3_t*)&Bs[buf][(w * 2 + 1) * 512], 16, 0, 0); \
    if (w < 2)                                                                       \
        __builtin_amdgcn_global_load_lds((const as1_t*)(wb + (size_t)(ks) * 5120 +   \
                                         (8 + w) * 512 + lane * 8),                  \
                                         (as3_t*)&Bs[buf][(8 + w) * 512], 16, 0, 0); \
} while (0)

    f32x4 acc[CTILES];
#pragma unroll
    for (int ct = 0; ct < CTILES; ++ct) acc[ct] = (f32x4){0.f, 0.f, 0.f, 0.f};

    // read-side A: row w*16+lm, swizzled chunk positions
    const int rl = w * 16 + lm;
    const int h0 = ((2 * lk)     ^ (lm & 7)) * 4;
    const int h1 = ((2 * lk + 1) ^ (lm & 7)) * 4;

    STAGE(0, 0);
    __syncthreads();

    for (int ks = 0; ks < KSTEPS; ++ks) {
        if (ks + 1 < KSTEPS) STAGE(ks + 1, (ks + 1) & 1);   // issue early (T14)

        const float*  Ac = As[ks & 1];
        const __bf16* Bc = Bs[ks & 1];
        f32x4 x0 = *(const f32x4*)&Ac[rl * 32 + h0];
        f32x4 x1 = *(const f32x4*)&Ac[rl * 32 + h1];
        bf16x8 a;
        a[0] = (__bf16)x0[0]; a[1] = (__bf16)x0[1];
        a[2] = (__bf16)x0[2]; a[3] = (__bf16)x0[3];
        a[4] = (__bf16)x1[0]; a[5] = (__bf16)x1[1];
        a[6] = (__bf16)x1[2]; a[7] = (__bf16)x1[3];

#pragma unroll
        for (int ct = 0; ct < CTILES; ++ct) {
            bf16x8 bfr = *(const bf16x8*)&Bc[ct * 512 + lane * 8];
            acc[ct] = __builtin_amdgcn_mfma_f32_16x16x32_bf16(a, bfr, acc[ct], 0, 0, 0);
        }
        __syncthreads();   // drains stage(ks+1) + protects buf[ks&1] reuse
    }

    // epilogue: permuted coalesced store, same chunk layout as R3-R5:
    //   idx = (((n*128 + rw)*2 + mt)*5 + p)*64 + lane
    const int rw = rb * 2 + (w >> 1);
    const int mt = w & 1;
    const size_t cbase = ((((size_t)n * 128 + rw) * 2 + mt) * 5) * 64 + lane;
#pragma unroll
    for (int p = 0; p < 5; ++p) {
        bf16x8 pk;
#pragma unroll
        for (int j = 0; j < 8; ++j)
            pk[j] = (__bf16)acc[2 * p + (j >> 2)][j & 3];
        up[cbase + (size_t)p * 64] = __builtin_bit_cast(uint4, pk);
    }
#undef STAGE
}

// ---------------------------------------------------------------------------
// routing (unchanged from R4/R5): 4 consecutive batch rows per block.
// ---------------------------------------------------------------------------
__global__ __launch_bounds__(256) void routing(const uint4* __restrict__ up,
                                               const float* __restrict__ bbias,
                                               float* __restrict__ out) {
    __shared__ __bf16 ul[4][IN_CAPS * STR2];      // 41472 B
    __shared__ float  bl[4][IN_CAPS * OUT_CAPS];
    __shared__ float  cs[4][IN_CAPS * OUT_CAPS];
    __shared__ float  ss[4][NOUT];
    __shared__ float  vs[4][NOUT];
    __shared__ float  scale_s[4][16];

    const int t  = threadIdx.x;
    const int b0 = blockIdx.x * 4;
    const int rw = b0 >> 5;
    const int mt = (b0 >> 4) & 1;
    const int lk = (b0 >> 2) & 3;

    for (int c = t; c < 2560; c += 256) {
        int n   = c / 80;
        int rem = c - n * 80;
        int p   = rem >> 4;
        int lm  = rem & 15;
        size_t idx = ((((size_t)n * 128 + rw) * 2 + mt) * 5 + p) * 64 + lk * 16 + lm;
        bf16x8 v = __builtin_bit_cast(bf16x8, up[idx]);
#pragma unroll
        for (int j = 0; j < 8; ++j) {
            int ct = 2 * p + (j >> 2);
            int rr = j & 3;
            ul[rr][n * STR2 + ct * 16 + lm] = v[j];
        }
    }
    const int grp = t >> 6;
    const int g   = t & 63;
    for (int pp = g; pp < IN_CAPS * OUT_CAPS; pp += 64) bl[grp][pp] = bbias[pp];
    __syncthreads();

    for (int it = 0; it < 4; ++it) {
        if (it > 0) {
            for (int pp = g; pp < IN_CAPS * OUT_CAPS; pp += 64) {
                int n = pp & 31;
                int o = pp >> 5;
                float a = 0.f;
#pragma unroll
                for (int d = 0; d < 16; ++d)
                    a += (float)ul[grp][n * STR2 + o * 16 + d] * vs[grp][o * 16 + d];
                bl[grp][n * 10 + o] += a;
            }
            __syncthreads();
        }
        if (g < IN_CAPS) {
            float m = bl[grp][g * 10];
#pragma unroll
            for (int o = 1; o < 10; ++o) m = fmaxf(m, bl[grp][g * 10 + o]);
            float e[10];
            float sum = 0.f;
#pragma unroll
            for (int o = 0; o < 10; ++o) { e[o] = __expf(bl[grp][g * 10 + o] - m); sum += e[o]; }
            float inv = 1.0f / sum;
#pragma unroll
            for (int o = 0; o < 10; ++o) cs[grp][g * 10 + o] = e[o] * inv;
        }
        __syncthreads();
        for (int p = g; p < NOUT; p += 64) {
            int o = p >> 4;
            float a = 0.f;
#pragma unroll
            for (int nn = 0; nn < IN_CAPS; ++nn)
                a += cs[grp][nn * 10 + o] * (float)ul[grp][nn * STR2 + p];
            ss[grp][p] = a;
        }
        __syncthreads();
        if (g < OUT_CAPS) {
            float sq = 0.f;
#pragma unroll
            for (int d = 0; d < 16; ++d) { float x = ss[grp][g * 16 + d]; sq += x * x; }
            scale_s[grp][g] = sq / ((1.0f + sq) * sqrtf(sq));
        }
        __syncthreads();
        for (int p = g; p < NOUT; p += 64) vs[grp][p] = scale_s[grp][p >> 4] * ss[grp][p];
        __syncthreads();
    }

    for (int p = g; p < NOUT; p += 64)
        out[(size_t)(b0 + grp) * NOUT + p] = vs[grp][p];
}

// ---------------------------------------------------------------------------
extern "C" void kernel_launch(void* const* d_in, const int* in_sizes, int n_in,
                              void* d_out, int out_size, void* d_ws, size_t ws_size,
                              hipStream_t stream) {
    const float* caps  = (const float*)d_in[0];   // [4096][32][288]
    const float* W     = (const float*)d_in[1];   // [32][288][160]
    const float* bbias = (const float*)d_in[2];   // [32][10]
    float* out = (float*)d_out;                   // [4096][10][16]

    __bf16* Wf = (__bf16*)d_ws;                               // 2,949,120 B
    uint4*  up = (uint4*)((char*)d_ws + 2949120);             // 41,943,040 B

    prep_w<<<dim3(5760), dim3(256), 0, stream>>>(W, Wf);
    gemm_u<<<dim3(64, 32), dim3(256), 0, stream>>>(caps, Wf, up);
    routing<<<dim3(BATCH / 4), dim3(256), 0, stream>>>(up, bbias, out);
}